// Round 18
// baseline (221.090 us; speedup 1.0000x reference)
//
#include <hip/hip_runtime.h>
#include <hip/hip_bf16.h>
#include <math.h>

#define NPIX 262144          // 512*512
#define PI_D 3.14159265358979323846264338327950288

typedef __attribute__((ext_vector_type(8))) short v8s;           // bf16x8 MFMA fragment
typedef __attribute__((ext_vector_type(4))) float v4f;           // f32x4 accumulator
typedef __attribute__((ext_vector_type(4))) unsigned short v4u;

// ---------------- ws layout (byte offsets) ----------------
// 0        double stats[2]
// 64       double spart[64][2]
// 2048     double den[32][121]              ends 33,024
// 33280    double snn_part[32][64]          ends 49,664
// 49664    double shx[32]
// 49920    double shy[32]
// 50176    float  c2[32]
// 50304    float  partial[32][64][121]      ends 1,041,536
// 1041536  ushort gtab[32][2][2][512]       ends 1,172,608
// 1172608  ushort tsp[2][512][512]          ends 2,221,184
// 2221184  float  csum[32][64][512]         ends 6,415,488
// 6415488  float  csum2[32][64][512]        ends 10,609,792
// 10609792 chunk area: per image 1 MB (YThi/YTlo 512KB each)

__device__ inline unsigned short f2bf(float x){ return __bfloat16_as_ushort(__float2bfloat16(x)); }
__device__ inline float bf2f(unsigned short h){ return __bfloat162float(__ushort_as_bfloat16(h)); }

// K1a: template partial sums
__global__ __launch_bounds__(256) void k_stats_part(const float* __restrict__ t, double* __restrict__ part){
    int base = blockIdx.x * 4096;
    double s = 0.0, s2 = 0.0;
    #pragma unroll
    for (int k = 0; k < 4; ++k){
        float4 v = *(const float4*)&t[base + k*1024 + threadIdx.x*4];
        s  += (double)v.x + (double)v.y + (double)v.z + (double)v.w;
        s2 += (double)v.x*v.x + (double)v.y*v.y + (double)v.z*v.z + (double)v.w*v.w;
    }
    __shared__ double rs[256], rs2[256];
    rs[threadIdx.x] = s; rs2[threadIdx.x] = s2; __syncthreads();
    for (int off = 128; off > 0; off >>= 1){
        if (threadIdx.x < off){ rs[threadIdx.x] += rs[threadIdx.x+off]; rs2[threadIdx.x] += rs2[threadIdx.x+off]; }
        __syncthreads();
    }
    if (threadIdx.x == 0){ part[blockIdx.x*2] = rs[0]; part[blockIdx.x*2+1] = rs2[0]; }
}

__global__ __launch_bounds__(64) void k_stats_final(const double* __restrict__ part, double* __restrict__ stats){
    double s = part[threadIdx.x*2], s2 = part[threadIdx.x*2+1];
    #pragma unroll
    for (int off = 32; off > 0; off >>= 1){
        s  += __shfl_down(s, off);
        s2 += __shfl_down(s2, off);
    }
    if (threadIdx.x == 0){
        stats[0] = s / (double)NPIX;
        stats[1] = s2 - s*s/(double)NPIX + 1e-8;
    }
}

// K1c: template -> zero-mean bf16 hi/lo
__global__ __launch_bounds__(256) void k_tsplit(const float* __restrict__ tpl, const double* __restrict__ stats,
                                                unsigned short* __restrict__ tsp){
    float mean = (float)stats[0];
    int base = blockIdx.x * 1024 + threadIdx.x * 4;
    float4 v = *(const float4*)&tpl[base];
    v.x -= mean; v.y -= mean; v.z -= mean; v.w -= mean;
    unsigned short h0 = f2bf(v.x), h1 = f2bf(v.y), h2 = f2bf(v.z), h3 = f2bf(v.w);
    v4u hv = {h0, h1, h2, h3};
    v4u lv = {f2bf(v.x - bf2f(h0)), f2bf(v.y - bf2f(h1)), f2bf(v.z - bf2f(h2)), f2bf(v.w - bf2f(h3))};
    *(v4u*)&tsp[base] = hv;
    *(v4u*)&tsp[262144 + base] = lv;
}

// K2b: finalize 121 window denominators (column sums come from k_ncc's 64 chunks)
__global__ __launch_bounds__(256) void k_winfin(const float* __restrict__ fr, const float* __restrict__ csum,
                                                const float* __restrict__ csum2, const double* __restrict__ stats,
                                                double* __restrict__ den){
    int b = blockIdx.x;
    const float* img = fr + (size_t)b * NPIX;
    __shared__ double fc[512], fc2[512];
    __shared__ double rsum[20], rsum2[20];
    __shared__ float E[20][20], E2[20][20];
    __shared__ double red[256], red2[256];
    int t = threadIdx.x;
    for (int c = t; c < 512; c += 256){
        double s = 0.0, s2 = 0.0;
        for (int k = 0; k < 64; ++k){
            size_t o = ((size_t)(b*64 + k) << 9) + c;
            s += (double)csum[o]; s2 += (double)csum2[o];
        }
        fc[c] = s; fc2[c] = s2;
    }
    if (t < 400){
        int i = t / 20, j = t % 20;
        int row = (i < 10) ? i : (i + 492);
        int col = (j < 10) ? j : (j + 492);
        float v = img[(row<<9) + col];
        E[i][j] = v; E2[i][j] = v*v;
    }
    __syncthreads();
    red[t] = fc[t] + fc[t+256];
    red2[t] = fc2[t] + fc2[t+256];
    __syncthreads();
    for (int off = 128; off > 0; off >>= 1){
        if (t < off){ red[t] += red[t+off]; red2[t] += red2[t+off]; }
        __syncthreads();
    }
    double F1 = red[0], F2 = red2[0];
    int lane = t & 63, wv = t >> 6;
    for (int e = wv; e < 20; e += 4){
        int row = (e < 10) ? e : (e + 492);
        double s = 0.0, s2 = 0.0;
        for (int c = lane; c < 512; c += 64){
            float v = img[(row<<9) + c];
            s += v; s2 += (double)v*v;
        }
        #pragma unroll
        for (int off = 32; off > 0; off >>= 1){ s += __shfl_down(s, off); s2 += __shfl_down(s2, off); }
        if (lane == 0){ rsum[e] = s; rsum2[e] = s2; }
    }
    __syncthreads();
    if (t < 121){
        int u = t / 11, v = t % 11;
        double S1 = F1, S2 = F2;
        for (int i = 0; i < u; ++i){ S1 -= rsum[i]; S2 -= rsum2[i]; }
        for (int k = 10+u; k < 20; ++k){ S1 -= rsum[k]; S2 -= rsum2[k]; }
        for (int j = 0; j < v; ++j){
            double cw = fc[j], cq = fc2[j];
            for (int i = 0; i < u; ++i){ cw -= E[i][j]; cq -= E2[i][j]; }
            for (int k = 10+u; k < 20; ++k){ cw -= E[k][j]; cq -= E2[k][j]; }
            S1 -= cw; S2 -= cq;
        }
        for (int jj = 10+v; jj < 20; ++jj){
            int col = jj + 492;
            double cw = fc[col], cq = fc2[col];
            for (int i = 0; i < u; ++i){ cw -= E[i][jj]; cq -= E2[i][jj]; }
            for (int k = 10+u; k < 20; ++k){ cw -= E[k][jj]; cq -= E2[k][jj]; }
            S1 -= cw; S2 -= cq;
        }
        const double K = 502.0*502.0;
        double ivar = S2/K - (S1*S1)/(K*K*K) + 1e-8;
        if (ivar < 0.0) ivar = 0.0;
        den[b*121 + u*11 + v] = sqrt(stats[1] * ivar);
    }
}

// K3: MFMA NCC + fused colsums (R17-verified)
__global__ __launch_bounds__(256, 2) void k_ncc(const float* __restrict__ fr,
                                                const unsigned short* __restrict__ tsp,
                                                float* __restrict__ partial,
                                                float* __restrict__ csum, float* __restrict__ csum2,
                                                double* __restrict__ snn_part){
    int b = blockIdx.x >> 6, chunk = blockIdx.x & 63;
    int i0 = chunk << 3;
    int tid = threadIdx.x;
    __shared__ unsigned short Th[24][520], Tl[24][520];
    __shared__ unsigned short Xh[8][544], Xl[8][544];
    __shared__ float Dred[4][16][16];
    __shared__ double snred[4];
    for (int q = tid; q < 1536; q += 256){
        int r = q >> 6, c8 = (q & 63) << 3;
        int grow = (i0 - 5 + r + 512) & 511;
        *(float4*)&Th[r][c8] = *(const float4*)&tsp[((size_t)grow << 9) + c8];
        *(float4*)&Tl[r][c8] = *(const float4*)&tsp[262144 + ((size_t)grow << 9) + c8];
    }
    const float* img = fr + ((size_t)b << 18);
    for (int q = tid; q < 1088; q += 256){
        int r = q / 136, qq = q - r*136;
        int col = ((qq << 2) - 16) & 511;
        float4 v = *(const float4*)&img[((size_t)(i0 + r) << 9) + col];
        unsigned short h0 = f2bf(v.x), h1 = f2bf(v.y), h2 = f2bf(v.z), h3 = f2bf(v.w);
        v4u hv = {h0, h1, h2, h3};
        v4u lv = {f2bf(v.x - bf2f(h0)), f2bf(v.y - bf2f(h1)), f2bf(v.z - bf2f(h2)), f2bf(v.w - bf2f(h3))};
        *(v4u*)&Xh[r][qq << 2] = hv;
        *(v4u*)&Xl[r][qq << 2] = lv;
    }
    __syncthreads();                                   // barrier 1: staging complete
    int l = tid & 63, wv = tid >> 6;
    {
        int c0 = tid << 1;
        float s0=0.f, q0=0.f, s1=0.f, q1=0.f;
        double sn = 0.0;
        #pragma unroll
        for (int r = 0; r < 8; ++r){
            unsigned uh = *(const unsigned*)&Xh[r][c0 + 16];
            unsigned ul = *(const unsigned*)&Xl[r][c0 + 16];
            float v0 = bf2f((unsigned short)uh) + bf2f((unsigned short)ul);
            float v1 = bf2f((unsigned short)(uh >> 16)) + bf2f((unsigned short)(ul >> 16));
            s0 += v0; q0 += v0*v0; s1 += v1; q1 += v1*v1;
            float d = v0 - v1;
            sn += ((i0 + r) & 1) ? -(double)d : (double)d;
        }
        size_t o = ((size_t)(b*64 + chunk) << 9) + c0;
        float2 cs = {s0, s1}, cq = {q0, q1};
        *(float2*)&csum[o] = cs;
        *(float2*)&csum2[o] = cq;
        #pragma unroll
        for (int off = 32; off > 0; off >>= 1) sn += __shfl_down(sn, off);
        if (l == 0) snred[wv] = sn;
    }
    int lr = l & 15, lk = l >> 4;
    v4f acc = (v4f){0.f, 0.f, 0.f, 0.f};
    union UB { unsigned u[4]; v8s s; };
    int sbase = (lk << 3) - lr + 21;
    unsigned sh = (unsigned)((sbase & 1) << 4);
    #pragma unroll
    for (int ii = 0; ii < 2; ++ii){
        int ro = 2*wv + ii;
        const unsigned* xh32 = (const unsigned*)&Xh[ro][0];
        const unsigned* xl32 = (const unsigned*)&Xl[ro][0];
        #pragma unroll 1
        for (int ks = 0; ks < 16; ++ks){
            int ka = (ks << 5) + (lk << 3);
            v8s ah = *(v8s*)&Th[ro + lr][ka];
            v8s al = *(v8s*)&Tl[ro + lr][ka];
            int W = ((ks << 5) + sbase) >> 1;
            unsigned wh[5], wl[5];
            #pragma unroll
            for (int j = 0; j < 5; ++j){ wh[j] = xh32[W + j]; wl[j] = xl32[W + j]; }
            UB bh, bl;
            #pragma unroll
            for (int j = 0; j < 4; ++j){
                bh.u[j] = __builtin_amdgcn_alignbit(wh[j+1], wh[j], sh);
                bl.u[j] = __builtin_amdgcn_alignbit(wl[j+1], wl[j], sh);
            }
            acc = __builtin_amdgcn_mfma_f32_16x16x32_bf16(ah, bh.s, acc, 0, 0, 0);
            acc = __builtin_amdgcn_mfma_f32_16x16x32_bf16(al, bh.s, acc, 0, 0, 0);
            acc = __builtin_amdgcn_mfma_f32_16x16x32_bf16(ah, bl.s, acc, 0, 0, 0);
        }
    }
    #pragma unroll
    for (int r = 0; r < 4; ++r) Dred[wv][4*lk + r][lr] = acc[r];
    __syncthreads();                                   // barrier 2: Dred + snred visible
    if (tid < 121){
        int s0 = tid / 11, s1 = tid - s0*11;
        int dy = 10 - s0, dx = 10 - s1;
        partial[(size_t)(b*64 + chunk)*121 + tid] =
            Dred[0][dy][dx] + Dred[1][dy][dx] + Dred[2][dy][dx] + Dred[3][dy][dx];
    }
    if (tid == 0)
        snn_part[b*64 + chunk] = snred[0] + snred[1] + snred[2] + snred[3];
}

// K4: ncc finalize -> shifts, c2
__global__ __launch_bounds__(128) void k_shifts(const float* __restrict__ partial, const double* __restrict__ den,
                                                const double* __restrict__ snn_part, double* __restrict__ shx,
                                                double* __restrict__ shy, float* __restrict__ c2){
    int b = blockIdx.x;
    __shared__ double l[121], nc[121];
    for (int e = threadIdx.x; e < 121; e += 128){
        double s = 0.0;
        for (int c = 0; c < 64; ++c) s += (double)partial[(size_t)(b*64 + c)*121 + e];
        double nom = fabs(s);
        double v = nom / den[b*121 + e];
        if (v != v) v = 0.0;
        nc[e] = v;
        l[e] = log(v);
    }
    __syncthreads();
    if (threadIdx.x == 0){
        int am = 0; double best = nc[0];
        for (int e = 1; e < 121; ++e) if (nc[e] > best){ best = nc[e]; am = e; }
        int u = am / 11, v = am % 11;
        double sx = -(double)(u - 5), sy = -(double)(v - 5);
        int um1 = u - 1; if (um1 < 0) um1 += 11; if (um1 > 10) um1 = 10;
        int up1 = u + 1; if (up1 > 10) up1 = 10;
        int vm1 = v - 1; if (vm1 < 0) vm1 += 11; if (vm1 > 10) vm1 = 10;
        int vp1 = v + 1; if (vp1 > 10) vp1 = 10;
        double l0x4 = 4.0 * l[u*11 + v];
        double lm = l[um1*11 + v], lp = l[up1*11 + v];
        sx -= (lm - lp) / (2.0*lm - l0x4 + 2.0*lp);
        double lm2 = l[u*11 + vm1], lp2 = l[u*11 + vp1];
        sy -= (lm2 - lp2) / (2.0*lm2 - l0x4 + 2.0*lp2);
        shx[b] = sx; shy[b] = sy;
        double snn = 0.0;
        for (int c = 0; c < 64; ++c) snn += snn_part[b*64 + c];
        double kx = sin(PI_D * sx) / 512.0, ky = sin(PI_D * sy) / 512.0;
        c2[b] = (float)(kx * ky * snn);
    }
}

__device__ inline double grekern(int t, double s){
    double u = (double)t - s;
    if (u > 256.0) u -= 512.0;
    double a = PI_D * u / 512.0;
    double sp = sin(a);
    double D;
    if (fabs(sp) < 1e-12) D = cos(PI_D * u) / cos(a);
    else D = sin(PI_D * u) / (512.0 * sp);
    return D * cos(a);
}

// K4b: Dirichlet kernels -> bf16 hi/lo tables
__global__ __launch_bounds__(256) void k_tables(const double* __restrict__ shx, const double* __restrict__ shy,
                                                unsigned short* __restrict__ gtab){
    int b = blockIdx.x;
    double sx = shx[b], sy = shy[b];
    unsigned short* g = gtab + ((size_t)b << 11);
    for (int t = threadIdx.x; t < 512; t += 256){
        float gy = (float)grekern(t, sy);
        float gx = (float)grekern(t, sx);
        unsigned short yh = f2bf(gy); unsigned short yl = f2bf(gy - bf2f(yh));
        unsigned short xh = f2bf(gx); unsigned short xl = f2bf(gx - bf2f(xh));
        g[t] = yh; g[512 + t] = yl; g[1024 + t] = xh; g[1536 + t] = xl;
    }
}

// K7a: stage-1 MFMA circulant GEMM (splitx fused, T14 prefetch — R15/16/17-verified compute)
// + NEW: transposed epilogue — C-tile -> LDS u32 tile P (pack hi|lo<<16), read transposed,
// write YThi/YTlo directly (kills k_transpose2 + the f32 Y round trip).
__global__ __launch_bounds__(256) void k_gemmA(const float* __restrict__ fr,
                                               const unsigned short* __restrict__ gtab,
                                               unsigned short* __restrict__ YThi,
                                               unsigned short* __restrict__ YTlo, int b0, int swz){
    int bid = blockIdx.x;
    int lb, tile;
    if (swz){ int x = bid & 7; int r = bid >> 3; lb = (r >> 4)*8 + x; tile = r & 15; }
    else    { lb = bid >> 4; tile = bid & 15; }
    int mt = tile >> 2, nt = tile & 3;
    int tid = threadIdx.x;
    __shared__ unsigned short Ath[128][40], Atl[128][40];   // 80B rows: 16B-aligned b128 reads
    __shared__ unsigned short grh[1024], grl[1024];
    __shared__ unsigned P[32][136];                          // pad 136: write-side 4-way banks
    int bg = b0 + lb;
    const unsigned short* gax = gtab + ((size_t)bg << 11);  // axis 0 (gy)
    for (int i = tid; i < 1024; i += 256){
        int src = (512 - (i & 511)) & 511;
        grh[i] = gax[src];
        grl[i] = gax[512 + src];
    }
    v4f acc[4][4];
    #pragma unroll
    for (int mi = 0; mi < 4; ++mi)
        #pragma unroll
        for (int ni = 0; ni < 4; ++ni) acc[mi][ni] = (v4f){0.f, 0.f, 0.f, 0.f};
    const float* img = fr + ((size_t)bg << 18) + (size_t)mt*128*512;
    int l = tid & 63, wv = tid >> 6;
    int wm = wv >> 1, wn = wv & 1;
    int lr = l & 15, lk = l >> 4;
    int colb = nt*128 + wn*64 + lr;
    unsigned sh = (unsigned)((colb & 1) << 4);
    const unsigned* grh32 = (const unsigned*)grh;
    const unsigned* grl32 = (const unsigned*)grl;
    union UB { unsigned u[4]; v8s s; };
    int rbase = tid >> 3, qoff = (tid & 7) << 2;
    float4 pf0 = *(const float4*)&img[(size_t)(rbase      )*512 + qoff];
    float4 pf1 = *(const float4*)&img[(size_t)(rbase + 32 )*512 + qoff];
    float4 pf2 = *(const float4*)&img[(size_t)(rbase + 64 )*512 + qoff];
    float4 pf3 = *(const float4*)&img[(size_t)(rbase + 96 )*512 + qoff];
    #pragma unroll 1
    for (int ks = 0; ks < 16; ++ks){
        __syncthreads();
        {
            float4 vv[4] = {pf0, pf1, pf2, pf3};
            #pragma unroll
            for (int p = 0; p < 4; ++p){
                float4 v = vv[p];
                unsigned short h0 = f2bf(v.x), h1 = f2bf(v.y), h2 = f2bf(v.z), h3 = f2bf(v.w);
                v4u hv = {h0, h1, h2, h3};
                v4u lv = {f2bf(v.x - bf2f(h0)), f2bf(v.y - bf2f(h1)), f2bf(v.z - bf2f(h2)), f2bf(v.w - bf2f(h3))};
                *(v4u*)&Ath[rbase + 32*p][qoff] = hv;
                *(v4u*)&Atl[rbase + 32*p][qoff] = lv;
            }
        }
        __syncthreads();
        v8s bhs[4], bls[4];
        #pragma unroll
        for (int ni = 0; ni < 4; ++ni){
            int f = ((ks << 5) + (lk << 3) - (colb + ni*16)) & 511;
            int W = f >> 1;
            unsigned wh[5], wl[5];
            #pragma unroll
            for (int j = 0; j < 5; ++j){ wh[j] = grh32[W + j]; wl[j] = grl32[W + j]; }
            UB bh, bl;
            #pragma unroll
            for (int j = 0; j < 4; ++j){
                bh.u[j] = __builtin_amdgcn_alignbit(wh[j+1], wh[j], sh);
                bl.u[j] = __builtin_amdgcn_alignbit(wl[j+1], wl[j], sh);
            }
            bhs[ni] = bh.s; bls[ni] = bl.s;
        }
        if (ks < 15){
            int c0 = ((ks + 1) << 5) + qoff;
            pf0 = *(const float4*)&img[(size_t)(rbase      )*512 + c0];
            pf1 = *(const float4*)&img[(size_t)(rbase + 32 )*512 + c0];
            pf2 = *(const float4*)&img[(size_t)(rbase + 64 )*512 + c0];
            pf3 = *(const float4*)&img[(size_t)(rbase + 96 )*512 + c0];
        }
        #pragma unroll
        for (int mi = 0; mi < 4; ++mi){
            int row = wm*64 + mi*16 + lr;
            v8s ah = *(v8s*)&Ath[row][lk*8];
            v8s al = *(v8s*)&Atl[row][lk*8];
            #pragma unroll
            for (int ni = 0; ni < 4; ++ni){
                acc[mi][ni] = __builtin_amdgcn_mfma_f32_16x16x32_bf16(ah, bhs[ni], acc[mi][ni], 0, 0, 0);
                acc[mi][ni] = __builtin_amdgcn_mfma_f32_16x16x32_bf16(al, bhs[ni], acc[mi][ni], 0, 0, 0);
                acc[mi][ni] = __builtin_amdgcn_mfma_f32_16x16x32_bf16(ah, bls[ni], acc[mi][ni], 0, 0, 0);
            }
        }
    }
    // --- transposed epilogue: 4 strips of 32 cols; P[c_l][r_l] = pack(hi, lo) ---
    unsigned short* dsth = YThi + ((size_t)lb << 18);
    unsigned short* dstl = YTlo + ((size_t)lb << 18);
    int crow4 = lk * 4;
    #pragma unroll 1
    for (int s = 0; s < 4; ++s){
        __syncthreads();                        // previous strip reads done (and MFMA loop done)
        if (wn == (s >> 1)){
            #pragma unroll
            for (int ni2 = 0; ni2 < 2; ++ni2){
                int ni = ((s & 1) << 1) + ni2;
                int c_l = (ni2 << 4) + lr;
                #pragma unroll
                for (int mi = 0; mi < 4; ++mi)
                    #pragma unroll
                    for (int rg = 0; rg < 4; ++rg){
                        int r_l = wm*64 + mi*16 + crow4 + rg;
                        float v = acc[mi][ni][rg];
                        unsigned short h = f2bf(v);
                        unsigned short lo = f2bf(v - bf2f(h));
                        P[c_l][r_l] = (unsigned)h | ((unsigned)lo << 16);
                    }
            }
        }
        __syncthreads();
        {   // read transposed: tid -> (c_l, 16-wide row segment)
            int c_l = tid >> 3, seg = (tid & 7) << 4;
            unsigned w[16];
            #pragma unroll
            for (int q = 0; q < 4; ++q)
                *(uint4*)&w[4*q] = *(const uint4*)&P[c_l][seg + 4*q];
            unsigned short hv[16], lv[16];
            #pragma unroll
            for (int j = 0; j < 16; ++j){ hv[j] = (unsigned short)w[j]; lv[j] = (unsigned short)(w[j] >> 16); }
            size_t o = ((size_t)(nt*128 + s*32 + c_l) << 9) + mt*128 + seg;
            *(v4u*)&dsth[o]     = *(v4u*)&hv[0];
            *(v4u*)&dsth[o + 4] = *(v4u*)&hv[4];
            *(v4u*)&dsth[o + 8] = *(v4u*)&hv[8];
            *(v4u*)&dsth[o +12] = *(v4u*)&hv[12];
            *(v4u*)&dstl[o]     = *(v4u*)&lv[0];
            *(v4u*)&dstl[o + 4] = *(v4u*)&lv[4];
            *(v4u*)&dstl[o + 8] = *(v4u*)&lv[8];
            *(v4u*)&dstl[o +12] = *(v4u*)&lv[12];
        }
    }
}

// K7: stage-2 MFMA circulant GEMM (R12-verified layout) + T14 prefetch (R15-verified).
template<int CORR>
__global__ __launch_bounds__(256) void k_gemm(const unsigned short* __restrict__ Ahi,
                                              const unsigned short* __restrict__ Alo,
                                              const unsigned short* __restrict__ gtab, int axis,
                                              float* __restrict__ Cout,
                                              const float* __restrict__ c2, int b0, int swz){
    int bid = blockIdx.x;
    int lb, tile;
    if (swz){ int x = bid & 7; int r = bid >> 3; lb = (r >> 4)*8 + x; tile = r & 15; }
    else    { lb = bid >> 4; tile = bid & 15; }
    int mt = tile >> 2, nt = tile & 3;
    int tid = threadIdx.x;
    __shared__ unsigned short Ath[128][40], Atl[128][40];
    __shared__ unsigned short grh[1024], grl[1024];
    int bg = b0 + lb;
    const unsigned short* gax = gtab + ((size_t)bg << 11) + (axis << 10);
    for (int i = tid; i < 1024; i += 256){
        int src = (512 - (i & 511)) & 511;
        grh[i] = gax[src];
        grl[i] = gax[512 + src];
    }
    v4f acc[4][4];
    #pragma unroll
    for (int mi = 0; mi < 4; ++mi)
        #pragma unroll
        for (int ni = 0; ni < 4; ++ni) acc[mi][ni] = (v4f){0.f, 0.f, 0.f, 0.f};
    const unsigned short* Aph = Ahi + ((size_t)lb << 18) + (size_t)mt*128*512;
    const unsigned short* Apl = Alo + ((size_t)lb << 18) + (size_t)mt*128*512;
    int l = tid & 63, wv = tid >> 6;
    int wm = wv >> 1, wn = wv & 1;
    int lr = l & 15, lk = l >> 4;
    int colb = nt*128 + wn*64 + lr;
    unsigned sh = (unsigned)((colb & 1) << 4);
    int srow = tid >> 1, sc = (tid & 1) << 4;
    const unsigned* grh32 = (const unsigned*)grh;
    const unsigned* grl32 = (const unsigned*)grl;
    union UB { unsigned u[4]; v8s s; };
    size_t go0 = (size_t)srow*512 + sc;
    float4 ph0 = *(const float4*)&Aph[go0];
    float4 ph1 = *(const float4*)&Aph[go0 + 8];
    float4 pl0 = *(const float4*)&Apl[go0];
    float4 pl1 = *(const float4*)&Apl[go0 + 8];
    #pragma unroll 1
    for (int ks = 0; ks < 16; ++ks){
        __syncthreads();
        { *(float4*)&Ath[srow][sc]     = ph0;
          *(float4*)&Ath[srow][sc + 8] = ph1;
          *(float4*)&Atl[srow][sc]     = pl0;
          *(float4*)&Atl[srow][sc + 8] = pl1; }
        __syncthreads();
        v8s bhs[4], bls[4];
        #pragma unroll
        for (int ni = 0; ni < 4; ++ni){
            int f = ((ks << 5) + (lk << 3) - (colb + ni*16)) & 511;
            int W = f >> 1;
            unsigned wh[5], wl[5];
            #pragma unroll
            for (int j = 0; j < 5; ++j){ wh[j] = grh32[W + j]; wl[j] = grl32[W + j]; }
            UB bh, bl;
            #pragma unroll
            for (int j = 0; j < 4; ++j){
                bh.u[j] = __builtin_amdgcn_alignbit(wh[j+1], wh[j], sh);
                bl.u[j] = __builtin_amdgcn_alignbit(wl[j+1], wl[j], sh);
            }
            bhs[ni] = bh.s; bls[ni] = bl.s;
        }
        if (ks < 15){
            size_t go = (size_t)srow*512 + ((ks + 1) << 5) + sc;
            ph0 = *(const float4*)&Aph[go];
            ph1 = *(const float4*)&Aph[go + 8];
            pl0 = *(const float4*)&Apl[go];
            pl1 = *(const float4*)&Apl[go + 8];
        }
        #pragma unroll
        for (int mi = 0; mi < 4; ++mi){
            int row = wm*64 + mi*16 + lr;
            v8s ah = *(v8s*)&Ath[row][lk*8];
            v8s al = *(v8s*)&Atl[row][lk*8];
            #pragma unroll
            for (int ni = 0; ni < 4; ++ni){
                acc[mi][ni] = __builtin_amdgcn_mfma_f32_16x16x32_bf16(ah, bhs[ni], acc[mi][ni], 0, 0, 0);
                acc[mi][ni] = __builtin_amdgcn_mfma_f32_16x16x32_bf16(al, bhs[ni], acc[mi][ni], 0, 0, 0);
                acc[mi][ni] = __builtin_amdgcn_mfma_f32_16x16x32_bf16(ah, bls[ni], acc[mi][ni], 0, 0, 0);
            }
        }
    }
    float cc = CORR ? c2[bg] : 0.f;
    float* outp = Cout + ((size_t)bg << 18);
    int crow4 = lk * 4;
    #pragma unroll
    for (int mi = 0; mi < 4; ++mi)
        #pragma unroll
        for (int ni = 0; ni < 4; ++ni)
            #pragma unroll
            for (int rg = 0; rg < 4; ++rg){
                int row = mt*128 + wm*64 + mi*16 + crow4 + rg;
                int col = nt*128 + wn*64 + ni*16 + lr;
                float v = acc[mi][ni][rg];
                if (CORR) v -= ((row + col) & 1) ? -cc : cc;
                outp[((size_t)row << 9) + col] = v;
            }
}

extern "C" void kernel_launch(void* const* d_in, const int* in_sizes, int n_in,
                              void* d_out, int out_size, void* d_ws, size_t ws_size,
                              hipStream_t stream){
    (void)in_sizes; (void)n_in; (void)out_size;
    const float* fr  = (const float*)d_in[0];
    const float* tpl = (const float*)d_in[1];
    float* out = (float*)d_out;
    char* ws = (char*)d_ws;

    double* stats  = (double*)(ws + 0);
    double* spart  = (double*)(ws + 64);
    double* den    = (double*)(ws + 2048);
    double* snnp   = (double*)(ws + 33280);
    double* shx    = (double*)(ws + 49664);
    double* shy    = (double*)(ws + 49920);
    float*  c2     = (float*) (ws + 50176);
    float*  part   = (float*) (ws + 50304);
    unsigned short* gtab = (unsigned short*)(ws + 1041536);
    unsigned short* tsp  = (unsigned short*)(ws + 1172608);
    float*  csum   = (float*) (ws + 2221184);
    float*  csum2  = (float*) (ws + 6415488);

    const size_t CB = 10609792;
    long long avail = ((long long)ws_size - (long long)CB) / (1ll << 20);
    int NC = (int)avail; if (NC > 32) NC = 32; if (NC < 1) NC = 1;
    if (NC >= 8) NC &= ~7;
    int swz = (NC % 8 == 0) ? 1 : 0;

    unsigned short* YThi = (unsigned short*)(ws + CB);
    unsigned short* YTlo = YThi + (size_t)NC*262144;

    k_stats_part<<<64, 256, 0, stream>>>(tpl, spart);
    k_stats_final<<<1, 64, 0, stream>>>(spart, stats);
    k_tsplit<<<256, 256, 0, stream>>>(tpl, stats, tsp);
    k_ncc<<<2048, 256, 0, stream>>>(fr, tsp, part, csum, csum2, snnp);
    k_winfin<<<32, 256, 0, stream>>>(fr, csum, csum2, stats, den);
    k_shifts<<<32, 128, 0, stream>>>(part, den, snnp, shx, shy, c2);
    k_tables<<<32, 256, 0, stream>>>(shx, shy, gtab);

    for (int b0 = 0; b0 < 32; b0 += NC){
        int nb = (32 - b0 < NC) ? (32 - b0) : NC;
        int sw = (swz && (nb % 8 == 0)) ? 1 : 0;
        // stage 1 (fused splitx + fused transpose): YT hi/lo directly
        k_gemmA<<<nb*16, 256, 0, stream>>>(fr, gtab, YThi, YTlo, b0, sw);
        // stage 2: Out = YT * Gx - c2*(-1)^(p+q) -> d_out (final)
        k_gemm<1><<<nb*16, 256, 0, stream>>>(YThi, YTlo, gtab, 1, out, c2, b0, sw);
    }
}

// Round 19
// 161.211 us; speedup vs baseline: 1.3714x; 1.3714x over previous
//
#include <hip/hip_runtime.h>
#include <hip/hip_bf16.h>
#include <math.h>

#define NPIX 262144          // 512*512
#define PI_D 3.14159265358979323846264338327950288

typedef __attribute__((ext_vector_type(8))) short v8s;           // bf16x8 MFMA fragment
typedef __attribute__((ext_vector_type(4))) float v4f;           // f32x4 accumulator
typedef __attribute__((ext_vector_type(4))) unsigned short v4u;

// ---------------- ws layout (byte offsets) ----------------
// 0        double stats[2]
// 64       double spart[64][2]
// 2048     double den[32][121]              ends 33,024
// 33280    double snn_part[32][64]          ends 49,664
// 49664    double shx[32]
// 49920    double shy[32]
// 50176    float  c2[32]
// 50304    float  partial[32][64][121]      ends 1,041,536
// 1041536  ushort gtab[32][2][2][512]       ends 1,172,608
// 1172608  ushort tsp[2][512][512]          ends 2,221,184
// 2221184  float  csum[32][64][512]         ends 6,415,488
// 6415488  float  csum2[32][64][512]        ends 10,609,792
// 10609792 chunk area: per image 1 MB (YThi/YTlo 512KB each)

__device__ inline unsigned short f2bf(float x){ return __bfloat16_as_ushort(__float2bfloat16(x)); }
__device__ inline float bf2f(unsigned short h){ return __bfloat162float(__ushort_as_bfloat16(h)); }

// K1a: template partial sums
__global__ __launch_bounds__(256) void k_stats_part(const float* __restrict__ t, double* __restrict__ part){
    int base = blockIdx.x * 4096;
    double s = 0.0, s2 = 0.0;
    #pragma unroll
    for (int k = 0; k < 4; ++k){
        float4 v = *(const float4*)&t[base + k*1024 + threadIdx.x*4];
        s  += (double)v.x + (double)v.y + (double)v.z + (double)v.w;
        s2 += (double)v.x*v.x + (double)v.y*v.y + (double)v.z*v.z + (double)v.w*v.w;
    }
    __shared__ double rs[256], rs2[256];
    rs[threadIdx.x] = s; rs2[threadIdx.x] = s2; __syncthreads();
    for (int off = 128; off > 0; off >>= 1){
        if (threadIdx.x < off){ rs[threadIdx.x] += rs[threadIdx.x+off]; rs2[threadIdx.x] += rs2[threadIdx.x+off]; }
        __syncthreads();
    }
    if (threadIdx.x == 0){ part[blockIdx.x*2] = rs[0]; part[blockIdx.x*2+1] = rs2[0]; }
}

__global__ __launch_bounds__(64) void k_stats_final(const double* __restrict__ part, double* __restrict__ stats){
    double s = part[threadIdx.x*2], s2 = part[threadIdx.x*2+1];
    #pragma unroll
    for (int off = 32; off > 0; off >>= 1){
        s  += __shfl_down(s, off);
        s2 += __shfl_down(s2, off);
    }
    if (threadIdx.x == 0){
        stats[0] = s / (double)NPIX;
        stats[1] = s2 - s*s/(double)NPIX + 1e-8;
    }
}

// K1c: template -> zero-mean bf16 hi/lo
__global__ __launch_bounds__(256) void k_tsplit(const float* __restrict__ tpl, const double* __restrict__ stats,
                                                unsigned short* __restrict__ tsp){
    float mean = (float)stats[0];
    int base = blockIdx.x * 1024 + threadIdx.x * 4;
    float4 v = *(const float4*)&tpl[base];
    v.x -= mean; v.y -= mean; v.z -= mean; v.w -= mean;
    unsigned short h0 = f2bf(v.x), h1 = f2bf(v.y), h2 = f2bf(v.z), h3 = f2bf(v.w);
    v4u hv = {h0, h1, h2, h3};
    v4u lv = {f2bf(v.x - bf2f(h0)), f2bf(v.y - bf2f(h1)), f2bf(v.z - bf2f(h2)), f2bf(v.w - bf2f(h3))};
    *(v4u*)&tsp[base] = hv;
    *(v4u*)&tsp[262144 + base] = lv;
}

// K2b: finalize 121 window denominators (column sums come from k_ncc's 64 chunks)
__global__ __launch_bounds__(256) void k_winfin(const float* __restrict__ fr, const float* __restrict__ csum,
                                                const float* __restrict__ csum2, const double* __restrict__ stats,
                                                double* __restrict__ den){
    int b = blockIdx.x;
    const float* img = fr + (size_t)b * NPIX;
    __shared__ double fc[512], fc2[512];
    __shared__ double rsum[20], rsum2[20];
    __shared__ float E[20][20], E2[20][20];
    __shared__ double red[256], red2[256];
    int t = threadIdx.x;
    for (int c = t; c < 512; c += 256){
        double s = 0.0, s2 = 0.0;
        for (int k = 0; k < 64; ++k){
            size_t o = ((size_t)(b*64 + k) << 9) + c;
            s += (double)csum[o]; s2 += (double)csum2[o];
        }
        fc[c] = s; fc2[c] = s2;
    }
    if (t < 400){
        int i = t / 20, j = t % 20;
        int row = (i < 10) ? i : (i + 492);
        int col = (j < 10) ? j : (j + 492);
        float v = img[(row<<9) + col];
        E[i][j] = v; E2[i][j] = v*v;
    }
    __syncthreads();
    red[t] = fc[t] + fc[t+256];
    red2[t] = fc2[t] + fc2[t+256];
    __syncthreads();
    for (int off = 128; off > 0; off >>= 1){
        if (t < off){ red[t] += red[t+off]; red2[t] += red2[t+off]; }
        __syncthreads();
    }
    double F1 = red[0], F2 = red2[0];
    int lane = t & 63, wv = t >> 6;
    for (int e = wv; e < 20; e += 4){
        int row = (e < 10) ? e : (e + 492);
        double s = 0.0, s2 = 0.0;
        for (int c = lane; c < 512; c += 64){
            float v = img[(row<<9) + c];
            s += v; s2 += (double)v*v;
        }
        #pragma unroll
        for (int off = 32; off > 0; off >>= 1){ s += __shfl_down(s, off); s2 += __shfl_down(s2, off); }
        if (lane == 0){ rsum[e] = s; rsum2[e] = s2; }
    }
    __syncthreads();
    if (t < 121){
        int u = t / 11, v = t % 11;
        double S1 = F1, S2 = F2;
        for (int i = 0; i < u; ++i){ S1 -= rsum[i]; S2 -= rsum2[i]; }
        for (int k = 10+u; k < 20; ++k){ S1 -= rsum[k]; S2 -= rsum2[k]; }
        for (int j = 0; j < v; ++j){
            double cw = fc[j], cq = fc2[j];
            for (int i = 0; i < u; ++i){ cw -= E[i][j]; cq -= E2[i][j]; }
            for (int k = 10+u; k < 20; ++k){ cw -= E[k][j]; cq -= E2[k][j]; }
            S1 -= cw; S2 -= cq;
        }
        for (int jj = 10+v; jj < 20; ++jj){
            int col = jj + 492;
            double cw = fc[col], cq = fc2[col];
            for (int i = 0; i < u; ++i){ cw -= E[i][jj]; cq -= E2[i][jj]; }
            for (int k = 10+u; k < 20; ++k){ cw -= E[k][jj]; cq -= E2[k][jj]; }
            S1 -= cw; S2 -= cq;
        }
        const double K = 502.0*502.0;
        double ivar = S2/K - (S1*S1)/(K*K*K) + 1e-8;
        if (ivar < 0.0) ivar = 0.0;
        den[b*121 + u*11 + v] = sqrt(stats[1] * ivar);
    }
}

// K3: MFMA NCC + fused colsums (R17-verified)
__global__ __launch_bounds__(256, 2) void k_ncc(const float* __restrict__ fr,
                                                const unsigned short* __restrict__ tsp,
                                                float* __restrict__ partial,
                                                float* __restrict__ csum, float* __restrict__ csum2,
                                                double* __restrict__ snn_part){
    int b = blockIdx.x >> 6, chunk = blockIdx.x & 63;
    int i0 = chunk << 3;
    int tid = threadIdx.x;
    __shared__ unsigned short Th[24][520], Tl[24][520];
    __shared__ unsigned short Xh[8][544], Xl[8][544];
    __shared__ float Dred[4][16][16];
    __shared__ double snred[4];
    for (int q = tid; q < 1536; q += 256){
        int r = q >> 6, c8 = (q & 63) << 3;
        int grow = (i0 - 5 + r + 512) & 511;
        *(float4*)&Th[r][c8] = *(const float4*)&tsp[((size_t)grow << 9) + c8];
        *(float4*)&Tl[r][c8] = *(const float4*)&tsp[262144 + ((size_t)grow << 9) + c8];
    }
    const float* img = fr + ((size_t)b << 18);
    for (int q = tid; q < 1088; q += 256){
        int r = q / 136, qq = q - r*136;
        int col = ((qq << 2) - 16) & 511;
        float4 v = *(const float4*)&img[((size_t)(i0 + r) << 9) + col];
        unsigned short h0 = f2bf(v.x), h1 = f2bf(v.y), h2 = f2bf(v.z), h3 = f2bf(v.w);
        v4u hv = {h0, h1, h2, h3};
        v4u lv = {f2bf(v.x - bf2f(h0)), f2bf(v.y - bf2f(h1)), f2bf(v.z - bf2f(h2)), f2bf(v.w - bf2f(h3))};
        *(v4u*)&Xh[r][qq << 2] = hv;
        *(v4u*)&Xl[r][qq << 2] = lv;
    }
    __syncthreads();                                   // barrier 1: staging complete
    int l = tid & 63, wv = tid >> 6;
    {
        int c0 = tid << 1;
        float s0=0.f, q0=0.f, s1=0.f, q1=0.f;
        double sn = 0.0;
        #pragma unroll
        for (int r = 0; r < 8; ++r){
            unsigned uh = *(const unsigned*)&Xh[r][c0 + 16];
            unsigned ul = *(const unsigned*)&Xl[r][c0 + 16];
            float v0 = bf2f((unsigned short)uh) + bf2f((unsigned short)ul);
            float v1 = bf2f((unsigned short)(uh >> 16)) + bf2f((unsigned short)(ul >> 16));
            s0 += v0; q0 += v0*v0; s1 += v1; q1 += v1*v1;
            float d = v0 - v1;
            sn += ((i0 + r) & 1) ? -(double)d : (double)d;
        }
        size_t o = ((size_t)(b*64 + chunk) << 9) + c0;
        float2 cs = {s0, s1}, cq = {q0, q1};
        *(float2*)&csum[o] = cs;
        *(float2*)&csum2[o] = cq;
        #pragma unroll
        for (int off = 32; off > 0; off >>= 1) sn += __shfl_down(sn, off);
        if (l == 0) snred[wv] = sn;
    }
    int lr = l & 15, lk = l >> 4;
    v4f acc = (v4f){0.f, 0.f, 0.f, 0.f};
    union UB { unsigned u[4]; v8s s; };
    int sbase = (lk << 3) - lr + 21;
    unsigned sh = (unsigned)((sbase & 1) << 4);
    #pragma unroll
    for (int ii = 0; ii < 2; ++ii){
        int ro = 2*wv + ii;
        const unsigned* xh32 = (const unsigned*)&Xh[ro][0];
        const unsigned* xl32 = (const unsigned*)&Xl[ro][0];
        #pragma unroll 1
        for (int ks = 0; ks < 16; ++ks){
            int ka = (ks << 5) + (lk << 3);
            v8s ah = *(v8s*)&Th[ro + lr][ka];
            v8s al = *(v8s*)&Tl[ro + lr][ka];
            int W = ((ks << 5) + sbase) >> 1;
            unsigned wh[5], wl[5];
            #pragma unroll
            for (int j = 0; j < 5; ++j){ wh[j] = xh32[W + j]; wl[j] = xl32[W + j]; }
            UB bh, bl;
            #pragma unroll
            for (int j = 0; j < 4; ++j){
                bh.u[j] = __builtin_amdgcn_alignbit(wh[j+1], wh[j], sh);
                bl.u[j] = __builtin_amdgcn_alignbit(wl[j+1], wl[j], sh);
            }
            acc = __builtin_amdgcn_mfma_f32_16x16x32_bf16(ah, bh.s, acc, 0, 0, 0);
            acc = __builtin_amdgcn_mfma_f32_16x16x32_bf16(al, bh.s, acc, 0, 0, 0);
            acc = __builtin_amdgcn_mfma_f32_16x16x32_bf16(ah, bl.s, acc, 0, 0, 0);
        }
    }
    #pragma unroll
    for (int r = 0; r < 4; ++r) Dred[wv][4*lk + r][lr] = acc[r];
    __syncthreads();                                   // barrier 2: Dred + snred visible
    if (tid < 121){
        int s0 = tid / 11, s1 = tid - s0*11;
        int dy = 10 - s0, dx = 10 - s1;
        partial[(size_t)(b*64 + chunk)*121 + tid] =
            Dred[0][dy][dx] + Dred[1][dy][dx] + Dred[2][dy][dx] + Dred[3][dy][dx];
    }
    if (tid == 0)
        snn_part[b*64 + chunk] = snred[0] + snred[1] + snred[2] + snred[3];
}

// K4: ncc finalize -> shifts, c2
__global__ __launch_bounds__(128) void k_shifts(const float* __restrict__ partial, const double* __restrict__ den,
                                                const double* __restrict__ snn_part, double* __restrict__ shx,
                                                double* __restrict__ shy, float* __restrict__ c2){
    int b = blockIdx.x;
    __shared__ double l[121], nc[121];
    for (int e = threadIdx.x; e < 121; e += 128){
        double s = 0.0;
        for (int c = 0; c < 64; ++c) s += (double)partial[(size_t)(b*64 + c)*121 + e];
        double nom = fabs(s);
        double v = nom / den[b*121 + e];
        if (v != v) v = 0.0;
        nc[e] = v;
        l[e] = log(v);
    }
    __syncthreads();
    if (threadIdx.x == 0){
        int am = 0; double best = nc[0];
        for (int e = 1; e < 121; ++e) if (nc[e] > best){ best = nc[e]; am = e; }
        int u = am / 11, v = am % 11;
        double sx = -(double)(u - 5), sy = -(double)(v - 5);
        int um1 = u - 1; if (um1 < 0) um1 += 11; if (um1 > 10) um1 = 10;
        int up1 = u + 1; if (up1 > 10) up1 = 10;
        int vm1 = v - 1; if (vm1 < 0) vm1 += 11; if (vm1 > 10) vm1 = 10;
        int vp1 = v + 1; if (vp1 > 10) vp1 = 10;
        double l0x4 = 4.0 * l[u*11 + v];
        double lm = l[um1*11 + v], lp = l[up1*11 + v];
        sx -= (lm - lp) / (2.0*lm - l0x4 + 2.0*lp);
        double lm2 = l[u*11 + vm1], lp2 = l[u*11 + vp1];
        sy -= (lm2 - lp2) / (2.0*lm2 - l0x4 + 2.0*lp2);
        shx[b] = sx; shy[b] = sy;
        double snn = 0.0;
        for (int c = 0; c < 64; ++c) snn += snn_part[b*64 + c];
        double kx = sin(PI_D * sx) / 512.0, ky = sin(PI_D * sy) / 512.0;
        c2[b] = (float)(kx * ky * snn);
    }
}

__device__ inline double grekern(int t, double s){
    double u = (double)t - s;
    if (u > 256.0) u -= 512.0;
    double a = PI_D * u / 512.0;
    double sp = sin(a);
    double D;
    if (fabs(sp) < 1e-12) D = cos(PI_D * u) / cos(a);
    else D = sin(PI_D * u) / (512.0 * sp);
    return D * cos(a);
}

// K4b: Dirichlet kernels -> bf16 hi/lo tables
__global__ __launch_bounds__(256) void k_tables(const double* __restrict__ shx, const double* __restrict__ shy,
                                                unsigned short* __restrict__ gtab){
    int b = blockIdx.x;
    double sx = shx[b], sy = shy[b];
    unsigned short* g = gtab + ((size_t)b << 11);
    for (int t = threadIdx.x; t < 512; t += 256){
        float gy = (float)grekern(t, sy);
        float gx = (float)grekern(t, sx);
        unsigned short yh = f2bf(gy); unsigned short yl = f2bf(gy - bf2f(yh));
        unsigned short xh = f2bf(gx); unsigned short xl = f2bf(gx - bf2f(xh));
        g[t] = yh; g[512 + t] = yl; g[1024 + t] = xh; g[1536 + t] = xl;
    }
}

// K7a: stage-1 MFMA circulant GEMM (splitx fused, T14 prefetch) + transposed epilogue.
// FIX vs R18: strip loop FULLY UNROLLED so acc[][] indices are compile-time constants
// (runtime ni spilled the whole accumulator to scratch: 515 MB writes, rule #20).
__global__ __launch_bounds__(256) void k_gemmA(const float* __restrict__ fr,
                                               const unsigned short* __restrict__ gtab,
                                               unsigned short* __restrict__ YThi,
                                               unsigned short* __restrict__ YTlo, int b0, int swz){
    int bid = blockIdx.x;
    int lb, tile;
    if (swz){ int x = bid & 7; int r = bid >> 3; lb = (r >> 4)*8 + x; tile = r & 15; }
    else    { lb = bid >> 4; tile = bid & 15; }
    int mt = tile >> 2, nt = tile & 3;
    int tid = threadIdx.x;
    __shared__ unsigned short Ath[128][40], Atl[128][40];   // 80B rows: 16B-aligned b128 reads
    __shared__ unsigned short grh[1024], grl[1024];
    __shared__ unsigned P[32][136];                          // pad 136: write-side 4-way banks
    int bg = b0 + lb;
    const unsigned short* gax = gtab + ((size_t)bg << 11);  // axis 0 (gy)
    for (int i = tid; i < 1024; i += 256){
        int src = (512 - (i & 511)) & 511;
        grh[i] = gax[src];
        grl[i] = gax[512 + src];
    }
    v4f acc[4][4];
    #pragma unroll
    for (int mi = 0; mi < 4; ++mi)
        #pragma unroll
        for (int ni = 0; ni < 4; ++ni) acc[mi][ni] = (v4f){0.f, 0.f, 0.f, 0.f};
    const float* img = fr + ((size_t)bg << 18) + (size_t)mt*128*512;
    int l = tid & 63, wv = tid >> 6;
    int wm = wv >> 1, wn = wv & 1;
    int lr = l & 15, lk = l >> 4;
    int colb = nt*128 + wn*64 + lr;
    unsigned sh = (unsigned)((colb & 1) << 4);
    const unsigned* grh32 = (const unsigned*)grh;
    const unsigned* grl32 = (const unsigned*)grl;
    union UB { unsigned u[4]; v8s s; };
    int rbase = tid >> 3, qoff = (tid & 7) << 2;
    float4 pf0 = *(const float4*)&img[(size_t)(rbase      )*512 + qoff];
    float4 pf1 = *(const float4*)&img[(size_t)(rbase + 32 )*512 + qoff];
    float4 pf2 = *(const float4*)&img[(size_t)(rbase + 64 )*512 + qoff];
    float4 pf3 = *(const float4*)&img[(size_t)(rbase + 96 )*512 + qoff];
    #pragma unroll 1
    for (int ks = 0; ks < 16; ++ks){
        __syncthreads();
        {
            float4 vv[4] = {pf0, pf1, pf2, pf3};
            #pragma unroll
            for (int p = 0; p < 4; ++p){
                float4 v = vv[p];
                unsigned short h0 = f2bf(v.x), h1 = f2bf(v.y), h2 = f2bf(v.z), h3 = f2bf(v.w);
                v4u hv = {h0, h1, h2, h3};
                v4u lv = {f2bf(v.x - bf2f(h0)), f2bf(v.y - bf2f(h1)), f2bf(v.z - bf2f(h2)), f2bf(v.w - bf2f(h3))};
                *(v4u*)&Ath[rbase + 32*p][qoff] = hv;
                *(v4u*)&Atl[rbase + 32*p][qoff] = lv;
            }
        }
        __syncthreads();
        v8s bhs[4], bls[4];
        #pragma unroll
        for (int ni = 0; ni < 4; ++ni){
            int f = ((ks << 5) + (lk << 3) - (colb + ni*16)) & 511;
            int W = f >> 1;
            unsigned wh[5], wl[5];
            #pragma unroll
            for (int j = 0; j < 5; ++j){ wh[j] = grh32[W + j]; wl[j] = grl32[W + j]; }
            UB bh, bl;
            #pragma unroll
            for (int j = 0; j < 4; ++j){
                bh.u[j] = __builtin_amdgcn_alignbit(wh[j+1], wh[j], sh);
                bl.u[j] = __builtin_amdgcn_alignbit(wl[j+1], wl[j], sh);
            }
            bhs[ni] = bh.s; bls[ni] = bl.s;
        }
        if (ks < 15){
            int c0 = ((ks + 1) << 5) + qoff;
            pf0 = *(const float4*)&img[(size_t)(rbase      )*512 + c0];
            pf1 = *(const float4*)&img[(size_t)(rbase + 32 )*512 + c0];
            pf2 = *(const float4*)&img[(size_t)(rbase + 64 )*512 + c0];
            pf3 = *(const float4*)&img[(size_t)(rbase + 96 )*512 + c0];
        }
        #pragma unroll
        for (int mi = 0; mi < 4; ++mi){
            int row = wm*64 + mi*16 + lr;
            v8s ah = *(v8s*)&Ath[row][lk*8];
            v8s al = *(v8s*)&Atl[row][lk*8];
            #pragma unroll
            for (int ni = 0; ni < 4; ++ni){
                acc[mi][ni] = __builtin_amdgcn_mfma_f32_16x16x32_bf16(ah, bhs[ni], acc[mi][ni], 0, 0, 0);
                acc[mi][ni] = __builtin_amdgcn_mfma_f32_16x16x32_bf16(al, bhs[ni], acc[mi][ni], 0, 0, 0);
                acc[mi][ni] = __builtin_amdgcn_mfma_f32_16x16x32_bf16(ah, bls[ni], acc[mi][ni], 0, 0, 0);
            }
        }
    }
    // --- transposed epilogue: 4 strips of 32 cols (FULLY unrolled: static acc indices) ---
    unsigned short* dsth = YThi + ((size_t)lb << 18);
    unsigned short* dstl = YTlo + ((size_t)lb << 18);
    int crow4 = lk * 4;
    #pragma unroll
    for (int s = 0; s < 4; ++s){
        __syncthreads();                        // previous strip reads done
        if (wn == (s >> 1)){
            #pragma unroll
            for (int ni2 = 0; ni2 < 2; ++ni2){
                int c_l = (ni2 << 4) + lr;
                #pragma unroll
                for (int mi = 0; mi < 4; ++mi)
                    #pragma unroll
                    for (int rg = 0; rg < 4; ++rg){
                        int r_l = wm*64 + mi*16 + crow4 + rg;
                        float v = acc[mi][((s & 1) << 1) + ni2][rg];   // all indices compile-time
                        unsigned short h = f2bf(v);
                        unsigned short lo = f2bf(v - bf2f(h));
                        P[c_l][r_l] = (unsigned)h | ((unsigned)lo << 16);
                    }
            }
        }
        __syncthreads();
        {   // read transposed: tid -> (c_l, 16-wide row segment)
            int c_l = tid >> 3, seg = (tid & 7) << 4;
            unsigned w[16];
            #pragma unroll
            for (int q = 0; q < 4; ++q)
                *(uint4*)&w[4*q] = *(const uint4*)&P[c_l][seg + 4*q];
            unsigned short hv[16], lv[16];
            #pragma unroll
            for (int j = 0; j < 16; ++j){ hv[j] = (unsigned short)w[j]; lv[j] = (unsigned short)(w[j] >> 16); }
            size_t o = ((size_t)(nt*128 + s*32 + c_l) << 9) + mt*128 + seg;
            *(v4u*)&dsth[o]     = *(v4u*)&hv[0];
            *(v4u*)&dsth[o + 4] = *(v4u*)&hv[4];
            *(v4u*)&dsth[o + 8] = *(v4u*)&hv[8];
            *(v4u*)&dsth[o +12] = *(v4u*)&hv[12];
            *(v4u*)&dstl[o]     = *(v4u*)&lv[0];
            *(v4u*)&dstl[o + 4] = *(v4u*)&lv[4];
            *(v4u*)&dstl[o + 8] = *(v4u*)&lv[8];
            *(v4u*)&dstl[o +12] = *(v4u*)&lv[12];
        }
    }
}

// K7: stage-2 MFMA circulant GEMM (R12-verified layout) + T14 prefetch (R15-verified).
template<int CORR>
__global__ __launch_bounds__(256) void k_gemm(const unsigned short* __restrict__ Ahi,
                                              const unsigned short* __restrict__ Alo,
                                              const unsigned short* __restrict__ gtab, int axis,
                                              float* __restrict__ Cout,
                                              const float* __restrict__ c2, int b0, int swz){
    int bid = blockIdx.x;
    int lb, tile;
    if (swz){ int x = bid & 7; int r = bid >> 3; lb = (r >> 4)*8 + x; tile = r & 15; }
    else    { lb = bid >> 4; tile = bid & 15; }
    int mt = tile >> 2, nt = tile & 3;
    int tid = threadIdx.x;
    __shared__ unsigned short Ath[128][40], Atl[128][40];
    __shared__ unsigned short grh[1024], grl[1024];
    int bg = b0 + lb;
    const unsigned short* gax = gtab + ((size_t)bg << 11) + (axis << 10);
    for (int i = tid; i < 1024; i += 256){
        int src = (512 - (i & 511)) & 511;
        grh[i] = gax[src];
        grl[i] = gax[512 + src];
    }
    v4f acc[4][4];
    #pragma unroll
    for (int mi = 0; mi < 4; ++mi)
        #pragma unroll
        for (int ni = 0; ni < 4; ++ni) acc[mi][ni] = (v4f){0.f, 0.f, 0.f, 0.f};
    const unsigned short* Aph = Ahi + ((size_t)lb << 18) + (size_t)mt*128*512;
    const unsigned short* Apl = Alo + ((size_t)lb << 18) + (size_t)mt*128*512;
    int l = tid & 63, wv = tid >> 6;
    int wm = wv >> 1, wn = wv & 1;
    int lr = l & 15, lk = l >> 4;
    int colb = nt*128 + wn*64 + lr;
    unsigned sh = (unsigned)((colb & 1) << 4);
    int srow = tid >> 1, sc = (tid & 1) << 4;
    const unsigned* grh32 = (const unsigned*)grh;
    const unsigned* grl32 = (const unsigned*)grl;
    union UB { unsigned u[4]; v8s s; };
    size_t go0 = (size_t)srow*512 + sc;
    float4 ph0 = *(const float4*)&Aph[go0];
    float4 ph1 = *(const float4*)&Aph[go0 + 8];
    float4 pl0 = *(const float4*)&Apl[go0];
    float4 pl1 = *(const float4*)&Apl[go0 + 8];
    #pragma unroll 1
    for (int ks = 0; ks < 16; ++ks){
        __syncthreads();
        { *(float4*)&Ath[srow][sc]     = ph0;
          *(float4*)&Ath[srow][sc + 8] = ph1;
          *(float4*)&Atl[srow][sc]     = pl0;
          *(float4*)&Atl[srow][sc + 8] = pl1; }
        __syncthreads();
        v8s bhs[4], bls[4];
        #pragma unroll
        for (int ni = 0; ni < 4; ++ni){
            int f = ((ks << 5) + (lk << 3) - (colb + ni*16)) & 511;
            int W = f >> 1;
            unsigned wh[5], wl[5];
            #pragma unroll
            for (int j = 0; j < 5; ++j){ wh[j] = grh32[W + j]; wl[j] = grl32[W + j]; }
            UB bh, bl;
            #pragma unroll
            for (int j = 0; j < 4; ++j){
                bh.u[j] = __builtin_amdgcn_alignbit(wh[j+1], wh[j], sh);
                bl.u[j] = __builtin_amdgcn_alignbit(wl[j+1], wl[j], sh);
            }
            bhs[ni] = bh.s; bls[ni] = bl.s;
        }
        if (ks < 15){
            size_t go = (size_t)srow*512 + ((ks + 1) << 5) + sc;
            ph0 = *(const float4*)&Aph[go];
            ph1 = *(const float4*)&Aph[go + 8];
            pl0 = *(const float4*)&Apl[go];
            pl1 = *(const float4*)&Apl[go + 8];
        }
        #pragma unroll
        for (int mi = 0; mi < 4; ++mi){
            int row = wm*64 + mi*16 + lr;
            v8s ah = *(v8s*)&Ath[row][lk*8];
            v8s al = *(v8s*)&Atl[row][lk*8];
            #pragma unroll
            for (int ni = 0; ni < 4; ++ni){
                acc[mi][ni] = __builtin_amdgcn_mfma_f32_16x16x32_bf16(ah, bhs[ni], acc[mi][ni], 0, 0, 0);
                acc[mi][ni] = __builtin_amdgcn_mfma_f32_16x16x32_bf16(al, bhs[ni], acc[mi][ni], 0, 0, 0);
                acc[mi][ni] = __builtin_amdgcn_mfma_f32_16x16x32_bf16(ah, bls[ni], acc[mi][ni], 0, 0, 0);
            }
        }
    }
    float cc = CORR ? c2[bg] : 0.f;
    float* outp = Cout + ((size_t)bg << 18);
    int crow4 = lk * 4;
    #pragma unroll
    for (int mi = 0; mi < 4; ++mi)
        #pragma unroll
        for (int ni = 0; ni < 4; ++ni)
            #pragma unroll
            for (int rg = 0; rg < 4; ++rg){
                int row = mt*128 + wm*64 + mi*16 + crow4 + rg;
                int col = nt*128 + wn*64 + ni*16 + lr;
                float v = acc[mi][ni][rg];
                if (CORR) v -= ((row + col) & 1) ? -cc : cc;
                outp[((size_t)row << 9) + col] = v;
            }
}

extern "C" void kernel_launch(void* const* d_in, const int* in_sizes, int n_in,
                              void* d_out, int out_size, void* d_ws, size_t ws_size,
                              hipStream_t stream){
    (void)in_sizes; (void)n_in; (void)out_size;
    const float* fr  = (const float*)d_in[0];
    const float* tpl = (const float*)d_in[1];
    float* out = (float*)d_out;
    char* ws = (char*)d_ws;

    double* stats  = (double*)(ws + 0);
    double* spart  = (double*)(ws + 64);
    double* den    = (double*)(ws + 2048);
    double* snnp   = (double*)(ws + 33280);
    double* shx    = (double*)(ws + 49664);
    double* shy    = (double*)(ws + 49920);
    float*  c2     = (float*) (ws + 50176);
    float*  part   = (float*) (ws + 50304);
    unsigned short* gtab = (unsigned short*)(ws + 1041536);
    unsigned short* tsp  = (unsigned short*)(ws + 1172608);
    float*  csum   = (float*) (ws + 2221184);
    float*  csum2  = (float*) (ws + 6415488);

    const size_t CB = 10609792;
    long long avail = ((long long)ws_size - (long long)CB) / (1ll << 20);
    int NC = (int)avail; if (NC > 32) NC = 32; if (NC < 1) NC = 1;
    if (NC >= 8) NC &= ~7;
    int swz = (NC % 8 == 0) ? 1 : 0;

    unsigned short* YThi = (unsigned short*)(ws + CB);
    unsigned short* YTlo = YThi + (size_t)NC*262144;

    k_stats_part<<<64, 256, 0, stream>>>(tpl, spart);
    k_stats_final<<<1, 64, 0, stream>>>(spart, stats);
    k_tsplit<<<256, 256, 0, stream>>>(tpl, stats, tsp);
    k_ncc<<<2048, 256, 0, stream>>>(fr, tsp, part, csum, csum2, snnp);
    k_winfin<<<32, 256, 0, stream>>>(fr, csum, csum2, stats, den);
    k_shifts<<<32, 128, 0, stream>>>(part, den, snnp, shx, shy, c2);
    k_tables<<<32, 256, 0, stream>>>(shx, shy, gtab);

    for (int b0 = 0; b0 < 32; b0 += NC){
        int nb = (32 - b0 < NC) ? (32 - b0) : NC;
        int sw = (swz && (nb % 8 == 0)) ? 1 : 0;
        // stage 1 (fused splitx + fused transpose): YT hi/lo directly
        k_gemmA<<<nb*16, 256, 0, stream>>>(fr, gtab, YThi, YTlo, b0, sw);
        // stage 2: Out = YT * Gx - c2*(-1)^(p+q) -> d_out (final)
        k_gemm<1><<<nb*16, 256, 0, stream>>>(YThi, YTlo, gtab, 1, out, c2, b0, sw);
    }
}